// Round 4
// baseline (258.576 us; speedup 1.0000x reference)
//
#include <hip/hip_runtime.h>

#define BB 32
#define TT 36
#define NN 10000
#define FF 3
#define HH 10
#define RR 20
#define NQ (NN / 4)                 // 2500 node-quads per batch
#define TOTQ (BB * TT * NQ)         // 2,880,000 (b,t,node-quad) cells
#define EXBLOCKS 720                // 2880 waves
#define QPW 1000                    // quads per wave (contiguous run)

// ws layout:
//   xz   : TOTQ float4           (compact channel-0, [B,T,N], 46 MB)
//   tm   : BB*NN floats          (per-(b,n) time mean, NaN if all-NaN)
//   rsum : BB*RR, rcnt : BB*RR, gsum, gcnt, g1

// Pass 1: macro-linear extraction of channel 0. Each wave owns a contiguous
// run of QPW quads (48 KB read / 16 KB write) -> streaming regime.
__global__ __launch_bounds__(256) void k_extract(
        const float4* __restrict__ seq4,
        float4* __restrict__ xz) {
    const int wave = (blockIdx.x * 256 + threadIdx.x) >> 6;
    const int lane = threadIdx.x & 63;
    const int base = wave * QPW;
    #pragma unroll 4
    for (int k = 0; k < (QPW + 63) / 64; ++k) {
        const int off = k * 64 + lane;
        if (off < QPW) {
            const int q = base + off;           // quad index in [0, TOTQ)
            const float4* p = seq4 + (size_t)3 * q;
            float4 a0 = p[0];
            float4 a1 = p[1];
            float4 a2 = p[2];
            xz[q] = make_float4(a0.x, a0.w, a1.z, a2.y);  // NaNs pass through
        }
    }
}

// Pass 2: T-reduction from the compact (LLC-hot) buffer + region/global sums.
__global__ __launch_bounds__(256) void k_finish(
        const float4* __restrict__ xz,
        const int* __restrict__ cid,
        float* __restrict__ tm,
        float* __restrict__ rsum,
        float* __restrict__ rcnt,
        float* __restrict__ gsum,
        float* __restrict__ gcnt) {
    __shared__ float ls[RR];
    __shared__ float lc[RR];
    const int b = blockIdx.y;
    const int q = blockIdx.x * blockDim.x + threadIdx.x;
    if (threadIdx.x < RR) { ls[threadIdx.x] = 0.f; lc[threadIdx.x] = 0.f; }
    __syncthreads();

    float lsum = 0.f, lcnt = 0.f;
    if (q < NQ) {
        const float4* p = xz + (size_t)b * TT * NQ + q;
        float s0 = 0.f, s1 = 0.f, s2 = 0.f, s3 = 0.f;
        float c0 = 0.f, c1 = 0.f, c2 = 0.f, c3 = 0.f;
        #pragma unroll 6
        for (int t = 0; t < TT; ++t) {
            float4 v = p[(size_t)t * NQ];
            if (v.x == v.x) { s0 += v.x; c0 += 1.f; }
            if (v.y == v.y) { s1 += v.y; c1 += 1.f; }
            if (v.z == v.z) { s2 += v.z; c2 += 1.f; }
            if (v.w == v.w) { s3 += v.w; c3 += 1.f; }
        }
        const float nanf_ = __int_as_float(0x7fc00000);
        float m0 = (c0 > 0.f) ? s0 / c0 : nanf_;
        float m1 = (c1 > 0.f) ? s1 / c1 : nanf_;
        float m2 = (c2 > 0.f) ? s2 / c2 : nanf_;
        float m3 = (c3 > 0.f) ? s3 / c3 : nanf_;
        ((float4*)tm)[(size_t)b * NQ + q] = make_float4(m0, m1, m2, m3);

        const int4 r4 = ((const int4*)cid)[q];
        if (c0 > 0.f) { atomicAdd(&ls[r4.x], m0); atomicAdd(&lc[r4.x], 1.f); lsum += m0; lcnt += 1.f; }
        if (c1 > 0.f) { atomicAdd(&ls[r4.y], m1); atomicAdd(&lc[r4.y], 1.f); lsum += m1; lcnt += 1.f; }
        if (c2 > 0.f) { atomicAdd(&ls[r4.z], m2); atomicAdd(&lc[r4.z], 1.f); lsum += m2; lcnt += 1.f; }
        if (c3 > 0.f) { atomicAdd(&ls[r4.w], m3); atomicAdd(&lc[r4.w], 1.f); lsum += m3; lcnt += 1.f; }
    }

    for (int off = 32; off > 0; off >>= 1) {
        lsum += __shfl_down(lsum, off, 64);
        lcnt += __shfl_down(lcnt, off, 64);
    }
    if ((threadIdx.x & 63) == 0) {
        atomicAdd(gsum, lsum);
        atomicAdd(gcnt, lcnt);
    }

    __syncthreads();
    if (threadIdx.x < RR) {
        atomicAdd(&rsum[b * RR + threadIdx.x], ls[threadIdx.x]);
        atomicAdd(&rcnt[b * RR + threadIdx.x], lc[threadIdx.x]);
    }
}

// single block, 640 threads (B*R = 640)
__global__ void k_regional(const float* __restrict__ rsum,
                           const float* __restrict__ rcnt,
                           const float* __restrict__ gsum,
                           const float* __restrict__ gcnt,
                           float* __restrict__ g1out,
                           float* __restrict__ out_reg) {
    const int tid = threadIdx.x;
    __shared__ float ssum[10];
    __shared__ float scnt[10];
    __shared__ float g2s;

    float val = 0.f;
    int valid = 0;
    if (tid < BB * RR) {
        float c = rcnt[tid];
        if (c > 0.f) { val = rsum[tid] / c; valid = 1; }
    }

    float wsv = valid ? val : 0.f;
    float wcv = (float)valid;
    for (int off = 32; off > 0; off >>= 1) {
        wsv += __shfl_down(wsv, off, 64);
        wcv += __shfl_down(wcv, off, 64);
    }
    const int wave = tid >> 6;
    if ((tid & 63) == 0) { ssum[wave] = wsv; scnt[wave] = wcv; }
    __syncthreads();

    if (tid == 0) {
        float s = 0.f, c = 0.f;
        #pragma unroll
        for (int i = 0; i < 10; ++i) { s += ssum[i]; c += scnt[i]; }
        g2s = s / c;
        g1out[0] = gsum[0] / gcnt[0];
    }
    __syncthreads();

    if (tid < BB * RR) {
        const int b = tid / RR, r = tid % RR;
        const float o = valid ? val : g2s;
        #pragma unroll
        for (int h = 0; h < HH; ++h)
            out_reg[(size_t)(b * HH + h) * RR + r] = o;
    }
}

__global__ __launch_bounds__(256) void k_pred(
        const float* __restrict__ tm,
        const float* __restrict__ g1p,
        float* __restrict__ out) {
    const int b = blockIdx.y;
    const int q = blockIdx.x * blockDim.x + threadIdx.x;
    if (q >= NQ) return;
    const float g1 = g1p[0];
    float4 v = ((const float4*)tm)[(size_t)b * NQ + q];
    if (!(v.x == v.x)) v.x = g1;
    if (!(v.y == v.y)) v.y = g1;
    if (!(v.z == v.z)) v.z = g1;
    if (!(v.w == v.w)) v.w = g1;
    float4* o = (float4*)out + (size_t)b * HH * NQ + q;
    #pragma unroll
    for (int h = 0; h < HH; ++h)
        o[(size_t)h * NQ] = v;
}

extern "C" void kernel_launch(void* const* d_in, const int* in_sizes, int n_in,
                              void* d_out, int out_size, void* d_ws, size_t ws_size,
                              hipStream_t stream) {
    const float* seq = (const float*)d_in[0];
    const int*   cid = (const int*)d_in[1];
    float* out = (float*)d_out;

    float4* xz   = (float4*)d_ws;                     // TOTQ float4 (46 MB)
    float*  tm   = (float*)(xz + (size_t)TOTQ);       // BB*NN floats
    float*  rsum = tm + (size_t)BB * NN;              // BB*RR
    float*  rcnt = rsum + BB * RR;                    // BB*RR
    float*  gsum = rcnt + BB * RR;                    // 1
    float*  gcnt = gsum + 1;                          // 1
    float*  g1   = gcnt + 1;                          // 1

    hipMemsetAsync(rsum, 0, (size_t)(2 * BB * RR + 2) * sizeof(float), stream);

    dim3 blk(256);
    k_extract<<<EXBLOCKS, blk, 0, stream>>>((const float4*)seq, xz);
    dim3 grdB((NQ + 255) / 256, BB);        // 10 x 32
    k_finish<<<grdB, blk, 0, stream>>>(xz, cid, tm, rsum, rcnt, gsum, gcnt);
    k_regional<<<1, 640, 0, stream>>>(rsum, rcnt, gsum, gcnt, g1,
                                      out + (size_t)BB * HH * NN);
    k_pred<<<grdB, blk, 0, stream>>>(tm, g1, out);
}

// Round 5
// 249.679 us; speedup vs baseline: 1.0356x; 1.0356x over previous
//
#include <hip/hip_runtime.h>

#define BB 32
#define TT 36
#define NN 10000
#define FF 3
#define HH 10
#define RR 20
#define NQ (NN / 4)        // 2500 node-quads per batch
#define QPB 256            // quads per block strip
#define FPB (QPB * 3)      // 768 float4s per chunk (12 KB)
#define NSTRIP ((NQ + QPB - 1) / QPB)   // 10
#define TSPLIT 3
#define TPB (TT / TSPLIT)  // 12 timesteps per block

// XOR swizzle at float4 granularity: spreads the 12-word node-quad read
// stride across banks (lanes j, j+8, ... land on distinct banks).
__device__ __forceinline__ int swz(int f) { return f ^ ((f >> 3) & 7); }

// ws layout (float4 first):
//   psum : TSPLIT*BB*NQ float4   (3.84 MB)
//   pcnt : TSPLIT*BB*NQ float4   (3.84 MB)
//   tm   : BB*NN floats          (1.28 MB)
//   rsum : BB*RR, rcnt : BB*RR, gsum, gcnt, g1

// Pass 1: fully lane-coalesced seq sweep + in-register T-partial reduction.
__global__ __launch_bounds__(256) void k_reduce(
        const float4* __restrict__ seq4,
        float4* __restrict__ psum,
        float4* __restrict__ pcnt) {
    __shared__ float lds[FPB * 4];     // 12 KB, swizzled float4 slots
    const int strip = blockIdx.x;      // 0..9
    const int b     = blockIdx.y;      // 0..31
    const int z     = blockIdx.z;      // 0..TSPLIT-1
    const int tid   = threadIdx.x;
    const int q0    = strip * QPB;
    const int nq    = (NQ - q0 < QPB) ? (NQ - q0) : QPB;   // 256 or 196
    const int nf4   = nq * 3;

    const size_t rowstride = (size_t)NN * FF / 4;          // 7500 float4/t
    const float4* base = seq4 + (size_t)(b * TT + z * TPB) * rowstride + 3 * q0;

    const bool a0 = tid < nf4;
    const bool a1 = tid + 256 < nf4;
    const bool a2 = tid + 512 < nf4;

    float s0 = 0.f, s1 = 0.f, s2 = 0.f, s3 = 0.f;
    float c0 = 0.f, c1 = 0.f, c2 = 0.f, c3 = 0.f;

    // prefetch t=0 (lane-consecutive 16 B loads)
    float4 r0, r1, r2;
    if (a0) r0 = base[tid];
    if (a1) r1 = base[tid + 256];
    if (a2) r2 = base[tid + 512];

    for (int t = 0; t < TPB; ++t) {
        // stage current timestep into LDS (swizzled float4 slots)
        if (a0) ((float4*)lds)[swz(tid)]       = r0;
        if (a1) ((float4*)lds)[swz(tid + 256)] = r1;
        if (a2) ((float4*)lds)[swz(tid + 512)] = r2;
        // issue next timestep's loads before the barrier so they fly over
        // the LDS phase
        if (t + 1 < TPB) {
            const float4* p = base + (size_t)(t + 1) * rowstride;
            if (a0) r0 = p[tid];
            if (a1) r1 = p[tid + 256];
            if (a2) r2 = p[tid + 512];
        }
        __syncthreads();
        if (tid < nq) {
            // node-quad tid: channel-0 floats at words 12*tid + {0,3,6,9}
            const int w = 12 * tid;
            float v0 = lds[4 * swz((w    ) >> 2) + ((w    ) & 3)];
            float v1 = lds[4 * swz((w + 3) >> 2) + ((w + 3) & 3)];
            float v2 = lds[4 * swz((w + 6) >> 2) + ((w + 6) & 3)];
            float v3 = lds[4 * swz((w + 9) >> 2) + ((w + 9) & 3)];
            if (v0 == v0) { s0 += v0; c0 += 1.f; }
            if (v1 == v1) { s1 += v1; c1 += 1.f; }
            if (v2 == v2) { s2 += v2; c2 += 1.f; }
            if (v3 == v3) { s3 += v3; c3 += 1.f; }
        }
        __syncthreads();
    }

    if (tid < nq) {
        const size_t o = (size_t)(z * BB + b) * NQ + q0 + tid;
        psum[o] = make_float4(s0, s1, s2, s3);
        pcnt[o] = make_float4(c0, c1, c2, c3);
    }
}

// Pass 2: merge TSPLIT partials -> per-node means + region/global sums.
__global__ __launch_bounds__(256) void k_finish(
        const float4* __restrict__ psum,
        const float4* __restrict__ pcnt,
        const int* __restrict__ cid,
        float* __restrict__ tm,
        float* __restrict__ rsum,
        float* __restrict__ rcnt,
        float* __restrict__ gsum,
        float* __restrict__ gcnt) {
    __shared__ float ls[RR];
    __shared__ float lc[RR];
    const int b = blockIdx.y;
    const int q = blockIdx.x * blockDim.x + threadIdx.x;
    if (threadIdx.x < RR) { ls[threadIdx.x] = 0.f; lc[threadIdx.x] = 0.f; }
    __syncthreads();

    float lsum = 0.f, lcnt = 0.f;
    if (q < NQ) {
        float s0 = 0.f, s1 = 0.f, s2 = 0.f, s3 = 0.f;
        float c0 = 0.f, c1 = 0.f, c2 = 0.f, c3 = 0.f;
        #pragma unroll
        for (int z = 0; z < TSPLIT; ++z) {
            const size_t o = (size_t)(z * BB + b) * NQ + q;
            float4 ps = psum[o];
            float4 pc = pcnt[o];
            s0 += ps.x; s1 += ps.y; s2 += ps.z; s3 += ps.w;
            c0 += pc.x; c1 += pc.y; c2 += pc.z; c3 += pc.w;
        }
        const float nanf_ = __int_as_float(0x7fc00000);
        float m0 = (c0 > 0.f) ? s0 / c0 : nanf_;
        float m1 = (c1 > 0.f) ? s1 / c1 : nanf_;
        float m2 = (c2 > 0.f) ? s2 / c2 : nanf_;
        float m3 = (c3 > 0.f) ? s3 / c3 : nanf_;
        ((float4*)tm)[(size_t)b * NQ + q] = make_float4(m0, m1, m2, m3);

        const int4 r4 = ((const int4*)cid)[q];
        if (c0 > 0.f) { atomicAdd(&ls[r4.x], m0); atomicAdd(&lc[r4.x], 1.f); lsum += m0; lcnt += 1.f; }
        if (c1 > 0.f) { atomicAdd(&ls[r4.y], m1); atomicAdd(&lc[r4.y], 1.f); lsum += m1; lcnt += 1.f; }
        if (c2 > 0.f) { atomicAdd(&ls[r4.z], m2); atomicAdd(&lc[r4.z], 1.f); lsum += m2; lcnt += 1.f; }
        if (c3 > 0.f) { atomicAdd(&ls[r4.w], m3); atomicAdd(&lc[r4.w], 1.f); lsum += m3; lcnt += 1.f; }
    }

    for (int off = 32; off > 0; off >>= 1) {
        lsum += __shfl_down(lsum, off, 64);
        lcnt += __shfl_down(lcnt, off, 64);
    }
    if ((threadIdx.x & 63) == 0) {
        atomicAdd(gsum, lsum);
        atomicAdd(gcnt, lcnt);
    }

    __syncthreads();
    if (threadIdx.x < RR) {
        atomicAdd(&rsum[b * RR + threadIdx.x], ls[threadIdx.x]);
        atomicAdd(&rcnt[b * RR + threadIdx.x], lc[threadIdx.x]);
    }
}

// single block, 640 threads (B*R = 640)
__global__ void k_regional(const float* __restrict__ rsum,
                           const float* __restrict__ rcnt,
                           const float* __restrict__ gsum,
                           const float* __restrict__ gcnt,
                           float* __restrict__ g1out,
                           float* __restrict__ out_reg) {
    const int tid = threadIdx.x;
    __shared__ float ssum[10];
    __shared__ float scnt[10];
    __shared__ float g2s;

    float val = 0.f;
    int valid = 0;
    if (tid < BB * RR) {
        float c = rcnt[tid];
        if (c > 0.f) { val = rsum[tid] / c; valid = 1; }
    }

    float wsv = valid ? val : 0.f;
    float wcv = (float)valid;
    for (int off = 32; off > 0; off >>= 1) {
        wsv += __shfl_down(wsv, off, 64);
        wcv += __shfl_down(wcv, off, 64);
    }
    const int wave = tid >> 6;
    if ((tid & 63) == 0) { ssum[wave] = wsv; scnt[wave] = wcv; }
    __syncthreads();

    if (tid == 0) {
        float s = 0.f, c = 0.f;
        #pragma unroll
        for (int i = 0; i < 10; ++i) { s += ssum[i]; c += scnt[i]; }
        g2s = s / c;
        g1out[0] = gsum[0] / gcnt[0];
    }
    __syncthreads();

    if (tid < BB * RR) {
        const int b = tid / RR, r = tid % RR;
        const float o = valid ? val : g2s;
        #pragma unroll
        for (int h = 0; h < HH; ++h)
            out_reg[(size_t)(b * HH + h) * RR + r] = o;
    }
}

__global__ __launch_bounds__(256) void k_pred(
        const float* __restrict__ tm,
        const float* __restrict__ g1p,
        float* __restrict__ out) {
    const int b = blockIdx.y;
    const int q = blockIdx.x * blockDim.x + threadIdx.x;
    if (q >= NQ) return;
    const float g1 = g1p[0];
    float4 v = ((const float4*)tm)[(size_t)b * NQ + q];
    if (!(v.x == v.x)) v.x = g1;
    if (!(v.y == v.y)) v.y = g1;
    if (!(v.z == v.z)) v.z = g1;
    if (!(v.w == v.w)) v.w = g1;
    float4* o = (float4*)out + (size_t)b * HH * NQ + q;
    #pragma unroll
    for (int h = 0; h < HH; ++h)
        o[(size_t)h * NQ] = v;
}

extern "C" void kernel_launch(void* const* d_in, const int* in_sizes, int n_in,
                              void* d_out, int out_size, void* d_ws, size_t ws_size,
                              hipStream_t stream) {
    const float* seq = (const float*)d_in[0];
    const int*   cid = (const int*)d_in[1];
    float* out = (float*)d_out;

    float4* psum = (float4*)d_ws;                          // TSPLIT*BB*NQ
    float4* pcnt = psum + (size_t)TSPLIT * BB * NQ;        // TSPLIT*BB*NQ
    float*  tm   = (float*)(pcnt + (size_t)TSPLIT * BB * NQ);  // BB*NN
    float*  rsum = tm + (size_t)BB * NN;                   // BB*RR
    float*  rcnt = rsum + BB * RR;                         // BB*RR
    float*  gsum = rcnt + BB * RR;                         // 1
    float*  gcnt = gsum + 1;                               // 1
    float*  g1   = gcnt + 1;                               // 1

    hipMemsetAsync(rsum, 0, (size_t)(2 * BB * RR + 2) * sizeof(float), stream);

    dim3 blk(256);
    dim3 grdA(NSTRIP, BB, TSPLIT);          // 10 x 32 x 3 = 960 blocks
    dim3 grdB((NQ + 255) / 256, BB);        // 10 x 32
    k_reduce<<<grdA, blk, 0, stream>>>((const float4*)seq, psum, pcnt);
    k_finish<<<grdB, blk, 0, stream>>>(psum, pcnt, cid, tm, rsum, rcnt, gsum, gcnt);
    k_regional<<<1, 640, 0, stream>>>(rsum, rcnt, gsum, gcnt, g1,
                                      out + (size_t)BB * HH * NN);
    k_pred<<<grdB, blk, 0, stream>>>(tm, g1, out);
}

// Round 6
// 214.790 us; speedup vs baseline: 1.2039x; 1.1624x over previous
//
#include <hip/hip_runtime.h>

#define BB 32
#define TT 36
#define NN 10000
#define FF 3
#define HH 10
#define RR 20
#define NQ (NN / 4)   // 2500 node-quads per batch

// ws layout (floats):
//   [0, BB*NN)      : time_mean (NaN where node all-NaN)
//   [+BB*RR]        : per-(b,region) sum of node means
//   [+BB*RR]        : per-(b,region) count of valid nodes
//   [+1]            : g1 (global nanmean of pred_speed)

__global__ __launch_bounds__(256) void k_time_mean(
        const float* __restrict__ seq,
        const int* __restrict__ cid,
        float* __restrict__ tm,
        float* __restrict__ rsum,
        float* __restrict__ rcnt) {
    __shared__ float ls[RR];
    __shared__ float lc[RR];
    const int b = blockIdx.y;
    const int q = blockIdx.x * blockDim.x + threadIdx.x;  // quad index 0..2499
    if (threadIdx.x < RR) { ls[threadIdx.x] = 0.f; lc[threadIdx.x] = 0.f; }
    __syncthreads();

    if (q < NQ) {
        // 4 nodes -> 12 consecutive floats per t -> 3 aligned float4 loads
        const float4* p = (const float4*)seq + (size_t)b * TT * NN * FF / 4 + 3 * q;
        const size_t tstride = (size_t)NN * FF / 4;  // 7500 float4s per t
        float s0 = 0.f, s1 = 0.f, s2 = 0.f, s3 = 0.f;
        int c0 = 0, c1 = 0, c2 = 0, c3 = 0;
        #pragma unroll
        for (int t = 0; t < TT; ++t) {
            float4 q0 = p[0];
            float4 q1 = p[1];
            float4 q2 = p[2];
            p += tstride;
            float v0 = q0.x, v1 = q0.w, v2 = q1.z, v3 = q2.y;
            if (v0 == v0) { s0 += v0; c0++; }
            if (v1 == v1) { s1 += v1; c1++; }
            if (v2 == v2) { s2 += v2; c2++; }
            if (v3 == v3) { s3 += v3; c3++; }
        }
        const float nanf_ = __int_as_float(0x7fc00000);
        float m0 = c0 ? s0 / (float)c0 : nanf_;
        float m1 = c1 ? s1 / (float)c1 : nanf_;
        float m2 = c2 ? s2 / (float)c2 : nanf_;
        float m3 = c3 ? s3 / (float)c3 : nanf_;
        ((float4*)tm)[(size_t)b * NQ + q] = make_float4(m0, m1, m2, m3);

        const int4 r4 = ((const int4*)cid)[q];
        if (c0) { atomicAdd(&ls[r4.x], m0); atomicAdd(&lc[r4.x], 1.f); }
        if (c1) { atomicAdd(&ls[r4.y], m1); atomicAdd(&lc[r4.y], 1.f); }
        if (c2) { atomicAdd(&ls[r4.z], m2); atomicAdd(&lc[r4.z], 1.f); }
        if (c3) { atomicAdd(&ls[r4.w], m3); atomicAdd(&lc[r4.w], 1.f); }
    }

    __syncthreads();
    // spread-address global atomics only: 640 distinct accumulators,
    // 10-way contention per address. No single-address herd.
    if (threadIdx.x < RR) {
        atomicAdd(&rsum[b * RR + threadIdx.x], ls[threadIdx.x]);
        atomicAdd(&rcnt[b * RR + threadIdx.x], lc[threadIdx.x]);
    }
}

// single block, 640 threads (B*R = 640 = 10 waves).
// Derives BOTH g2 (mean of regional values) and g1 (= sum rsum / sum rcnt,
// identical to the global nanmean over nodes) from the 640 accumulators.
__global__ void k_regional(const float* __restrict__ rsum,
                           const float* __restrict__ rcnt,
                           float* __restrict__ g1out,
                           float* __restrict__ out_reg) {
    const int tid = threadIdx.x;
    __shared__ float sv[10], sc[10], ss[10], sn[10];
    __shared__ float g2s;

    float myrs = 0.f, myrc = 0.f;
    float val = 0.f;
    int valid = 0;
    if (tid < BB * RR) {
        myrs = rsum[tid];
        myrc = rcnt[tid];
        if (myrc > 0.f) { val = myrs / myrc; valid = 1; }
    }

    // wave reductions: (regional-value sum, valid count) for g2,
    //                  (raw sum, raw count) for g1
    float wv = valid ? val : 0.f;
    float wc = (float)valid;
    float ws = myrs;
    float wn = myrc;
    for (int off = 32; off > 0; off >>= 1) {
        wv += __shfl_down(wv, off, 64);
        wc += __shfl_down(wc, off, 64);
        ws += __shfl_down(ws, off, 64);
        wn += __shfl_down(wn, off, 64);
    }
    const int wave = tid >> 6;
    if ((tid & 63) == 0) { sv[wave] = wv; sc[wave] = wc; ss[wave] = ws; sn[wave] = wn; }
    __syncthreads();

    if (tid == 0) {
        float v = 0.f, c = 0.f, s = 0.f, n = 0.f;
        #pragma unroll
        for (int i = 0; i < 10; ++i) { v += sv[i]; c += sc[i]; s += ss[i]; n += sn[i]; }
        g2s = v / c;            // nanmean over regional entries
        g1out[0] = s / n;       // global nanmean over node means
    }
    __syncthreads();

    if (tid < BB * RR) {
        const int b = tid / RR, r = tid % RR;
        const float o = valid ? val : g2s;
        #pragma unroll
        for (int h = 0; h < HH; ++h)
            out_reg[(size_t)(b * HH + h) * RR + r] = o;
    }
}

__global__ __launch_bounds__(256) void k_pred(
        const float* __restrict__ tm,
        const float* __restrict__ g1p,
        float* __restrict__ out) {
    const int b = blockIdx.y;
    const int q = blockIdx.x * blockDim.x + threadIdx.x;  // quad 0..2499
    if (q >= NQ) return;
    const float g1 = g1p[0];
    float4 v = ((const float4*)tm)[(size_t)b * NQ + q];
    if (!(v.x == v.x)) v.x = g1;
    if (!(v.y == v.y)) v.y = g1;
    if (!(v.z == v.z)) v.z = g1;
    if (!(v.w == v.w)) v.w = g1;
    float4* o = (float4*)out + (size_t)b * HH * NQ + q;
    #pragma unroll
    for (int h = 0; h < HH; ++h)
        o[(size_t)h * NQ] = v;
}

extern "C" void kernel_launch(void* const* d_in, const int* in_sizes, int n_in,
                              void* d_out, int out_size, void* d_ws, size_t ws_size,
                              hipStream_t stream) {
    const float* seq = (const float*)d_in[0];
    const int*   cid = (const int*)d_in[1];
    float* out = (float*)d_out;

    float* ws   = (float*)d_ws;
    float* tm   = ws;                     // BB*NN
    float* rsum = tm + BB * NN;           // BB*RR
    float* rcnt = rsum + BB * RR;         // BB*RR
    float* g1   = rcnt + BB * RR;         // 1

    hipMemsetAsync(rsum, 0, (size_t)(2 * BB * RR) * sizeof(float), stream);

    dim3 blk(256);
    dim3 grd((NQ + 255) / 256, BB);       // 10 x 32 = 320 blocks
    k_time_mean<<<grd, blk, 0, stream>>>(seq, cid, tm, rsum, rcnt);
    k_regional<<<1, 640, 0, stream>>>(rsum, rcnt, g1,
                                      out + (size_t)BB * HH * NN);
    k_pred<<<grd, blk, 0, stream>>>(tm, g1, out);
}